// Round 2
// baseline (335.257 us; speedup 1.0000x reference)
//
#include <hip/hip_runtime.h>

// OnlyMarkovConvolution: out[b,i] = mask[b,i] ? -1e8 : log_softmax_row(w[i]*m[b,i]+b[i])
// B=16384, N=2048. One wave64 per row-iteration; 32 elements/lane in registers.
// R1: w/b staged in LDS (removes 8 B/elem from the vector-global path, which R0
// showed is the ~10 B/cyc/CU bottleneck); mask prefetched to registers so each
// row has a single global-latency exposure.

#define BDIM 256
#define NCOLS 2048
#define ROWS_PER_WAVE 2

__global__ __launch_bounds__(BDIM) void markov_logsoftmax_kernel(
    const float* __restrict__ x_markov,
    const int*   __restrict__ x_mask,
    const float* __restrict__ conv_w,
    const float* __restrict__ conv_b,
    float*       __restrict__ out,
    int B)
{
    __shared__ float s_w[NCOLS];
    __shared__ float s_b[NCOLS];

    // Stage w/b once per block: 256 threads x 2 float4s each per array.
#pragma unroll
    for (int i = threadIdx.x; i < NCOLS / 4; i += BDIM) {
        ((float4*)s_w)[i] = ((const float4*)conv_w)[i];
        ((float4*)s_b)[i] = ((const float4*)conv_b)[i];
    }
    __syncthreads();

    const int wave = threadIdx.x >> 6;
    const int lane = threadIdx.x & 63;
    const int gwave = blockIdx.x * (BDIM / 64) + wave;
    const int nwaves = gridDim.x * (BDIM / 64);

    for (int r = gwave; r < B; r += nwaves) {
        const float* __restrict__ mrow = x_markov + (long long)r * NCOLS;
        const int*   __restrict__ krow = x_mask   + (long long)r * NCOLS;
        float*       __restrict__ orow = out      + (long long)r * NCOLS;

        float4 t[8];
        int4   msk[8];

        // Issue all 16 global loads for this row up front.
#pragma unroll
        for (int j = 0; j < 8; ++j) {
            const int idx = (j * 64 + lane) * 4;
            t[j] = *(const float4*)(mrow + idx);
        }
#pragma unroll
        for (int j = 0; j < 8; ++j) {
            const int idx = (j * 64 + lane) * 4;
            msk[j] = *(const int4*)(krow + idx);
        }

        // Affine from LDS w/b + running max.
        float vmax = -3.4e38f;
#pragma unroll
        for (int j = 0; j < 8; ++j) {
            const int idx = (j * 64 + lane) * 4;
            const float4 w = *(const float4*)(s_w + idx);
            const float4 b = *(const float4*)(s_b + idx);
            float4 v;
            v.x = fmaf(w.x, t[j].x, b.x);
            v.y = fmaf(w.y, t[j].y, b.y);
            v.z = fmaf(w.z, t[j].z, b.z);
            v.w = fmaf(w.w, t[j].w, b.w);
            t[j] = v;
            vmax = fmaxf(vmax, fmaxf(fmaxf(v.x, v.y), fmaxf(v.z, v.w)));
        }

        // Wave64 max reduction (butterfly).
#pragma unroll
        for (int off = 32; off >= 1; off >>= 1)
            vmax = fmaxf(vmax, __shfl_xor(vmax, off, 64));

        // Sum of exp(t - max).
        float sum = 0.f;
#pragma unroll
        for (int j = 0; j < 8; ++j) {
            sum += __expf(t[j].x - vmax);
            sum += __expf(t[j].y - vmax);
            sum += __expf(t[j].z - vmax);
            sum += __expf(t[j].w - vmax);
        }
#pragma unroll
        for (int off = 32; off >= 1; off >>= 1)
            sum += __shfl_xor(sum, off, 64);

        const float c = vmax + __logf(sum);   // t - c = log_softmax

        // Mask (already in registers) + store.
#pragma unroll
        for (int j = 0; j < 8; ++j) {
            const int idx = (j * 64 + lane) * 4;
            const float4 v = t[j];
            float4 o;
            o.x = msk[j].x ? -1e8f : (v.x - c);
            o.y = msk[j].y ? -1e8f : (v.y - c);
            o.z = msk[j].z ? -1e8f : (v.z - c);
            o.w = msk[j].w ? -1e8f : (v.w - c);
            *(float4*)(orow + idx) = o;
        }
    }
}

extern "C" void kernel_launch(void* const* d_in, const int* in_sizes, int n_in,
                              void* d_out, int out_size, void* d_ws, size_t ws_size,
                              hipStream_t stream) {
    // setup_inputs order: x(0), x_dist(1), x_features(2), x_markov(3),
    //                     x_week(4), x_mask(5), conv_w(6), conv_b(7)
    const float* x_markov = (const float*)d_in[3];
    const int*   x_mask   = (const int*)d_in[5];
    const float* conv_w   = (const float*)d_in[6];
    const float* conv_b   = (const float*)d_in[7];
    float* out = (float*)d_out;

    const int B = in_sizes[4];                       // 16384 (x_week is [B])
    const int grid = B / ((BDIM / 64) * ROWS_PER_WAVE);  // 2048 blocks

    markov_logsoftmax_kernel<<<grid, BDIM, 0, stream>>>(
        x_markov, x_mask, conv_w, conv_b, out, B);
}